// Round 1
// baseline (596.299 us; speedup 1.0000x reference)
//
#include <hip/hip_runtime.h>
#include <hip/hip_bf16.h>
#include <stdint.h>

typedef unsigned short u16;
typedef __attribute__((ext_vector_type(8))) __bf16 bf16x8;
typedef __attribute__((ext_vector_type(4))) float f32x4;
typedef __attribute__((ext_vector_type(4))) unsigned int u32x4;

#define S_LEN 2048
#define NHEAD 16
#define HDIM 64
#define DMODEL 1024
#define NBATCH 4
#define MTOK (NBATCH * S_LEN)   // 8192

// ---------- helpers ----------
__device__ __forceinline__ u16 f2bf(float f) {
    uint32_t u = __float_as_uint(f);
    u += 0x7fffu + ((u >> 16) & 1u);   // RNE
    return (u16)(u >> 16);
}

// ---------- fp32 -> bf16 cast ----------
__global__ void cast_kernel(const float* __restrict__ src, u16* __restrict__ dst, int n) {
    int i = (blockIdx.x * 256 + threadIdx.x) * 4;
    if (i + 3 < n) {
        float4 v = *(const float4*)(src + i);
        ushort4 o;
        o.x = f2bf(v.x); o.y = f2bf(v.y); o.z = f2bf(v.z); o.w = f2bf(v.w);
        *(ushort4*)(dst + i) = o;
    }
}

// ---------- GEMM: out[m,n] = sum_k A[m,k]*W[n,k] + bias[n] ----------
// mode 0: bf16 out, [B,H,S,D] layout (Q/K)
// mode 1: bf16 out, [B,H,D,S] layout (V transposed)
// mode 2: fp32 out, row-major [m,n] (final projection)
#define TM 128
#define TN 128
#define LDP 40   // 32 + 8 pad, keeps 16B alignment, breaks pow2 bank stride

__device__ __forceinline__ void gemm_body(const u16* __restrict__ A,
                                          const u16* __restrict__ W,
                                          const float* __restrict__ bias,
                                          void* __restrict__ outp, int mode) {
    __shared__ u16 As[TM * LDP];
    __shared__ u16 Bs[TN * LDP];
    const int tid  = threadIdx.x;
    const int lane = tid & 63;
    const int wv   = tid >> 6;
    const int l16  = lane & 15;
    const int quad = lane >> 4;
    const int wm   = (wv >> 1) * 64;
    const int wn   = (wv & 1) * 64;
    const int m0   = blockIdx.y * TM;
    const int n0   = blockIdx.x * TN;

    f32x4 acc[4][4];
#pragma unroll
    for (int i = 0; i < 4; i++)
#pragma unroll
        for (int j = 0; j < 4; j++) acc[i][j] = {};

    const int row0 = tid >> 2;   // 0..63
    const int c0   = tid & 3;    // 16B segment within 32-elem k-block

    for (int kb = 0; kb < DMODEL; kb += 32) {
        u32x4 a0 = *(const u32x4*)(A + (size_t)(m0 + row0) * DMODEL + kb + c0 * 8);
        u32x4 a1 = *(const u32x4*)(A + (size_t)(m0 + row0 + 64) * DMODEL + kb + c0 * 8);
        u32x4 b0 = *(const u32x4*)(W + (size_t)(n0 + row0) * DMODEL + kb + c0 * 8);
        u32x4 b1 = *(const u32x4*)(W + (size_t)(n0 + row0 + 64) * DMODEL + kb + c0 * 8);
        *(u32x4*)(&As[(row0) * LDP + c0 * 8])      = a0;
        *(u32x4*)(&As[(row0 + 64) * LDP + c0 * 8]) = a1;
        *(u32x4*)(&Bs[(row0) * LDP + c0 * 8])      = b0;
        *(u32x4*)(&Bs[(row0 + 64) * LDP + c0 * 8]) = b1;
        __syncthreads();

        bf16x8 af[4], bfv[4];
#pragma unroll
        for (int i = 0; i < 4; i++)
            af[i] = *(const bf16x8*)(&As[(wm + i * 16 + l16) * LDP + quad * 8]);
#pragma unroll
        for (int j = 0; j < 4; j++)
            bfv[j] = *(const bf16x8*)(&Bs[(wn + j * 16 + l16) * LDP + quad * 8]);
#pragma unroll
        for (int i = 0; i < 4; i++)
#pragma unroll
            for (int j = 0; j < 4; j++)
                acc[i][j] = __builtin_amdgcn_mfma_f32_16x16x32_bf16(af[i], bfv[j], acc[i][j], 0, 0, 0);
        __syncthreads();
    }

    // epilogue: C row = quad*4+r, col = l16 within each 16x16 tile
#pragma unroll
    for (int j = 0; j < 4; j++) {
        int n = n0 + wn + j * 16 + l16;
        float bv = bias[n];
#pragma unroll
        for (int i = 0; i < 4; i++) {
            int mbase = m0 + wm + i * 16 + quad * 4;
#pragma unroll
            for (int r = 0; r < 4; r++) {
                int m = mbase + r;
                float v = acc[i][j][r] + bv;
                if (mode == 2) {
                    ((float*)outp)[(size_t)m * DMODEL + n] = v;
                } else {
                    int b = m >> 11, s = m & (S_LEN - 1);
                    int h = n >> 6, d = n & 63;
                    u16* o = (u16*)outp;
                    size_t idx = (mode == 0)
                        ? ((((size_t)(b * NHEAD + h)) * S_LEN + s) * HDIM + d)
                        : ((((size_t)(b * NHEAD + h)) * HDIM + d) * S_LEN + s);
                    o[idx] = f2bf(v);
                }
            }
        }
    }
}

__global__ __launch_bounds__(256) void gemm_qkv(
        const u16* __restrict__ xq, const u16* __restrict__ xk, const u16* __restrict__ xv,
        const u16* __restrict__ wq, const u16* __restrict__ wk, const u16* __restrict__ wv,
        const float* __restrict__ bq, const float* __restrict__ bk, const float* __restrict__ bv,
        u16* __restrict__ Qb, u16* __restrict__ Kb, u16* __restrict__ Vb) {
    int z = blockIdx.z;
    const u16* A   = (z == 0) ? xq : (z == 1) ? xk : xv;
    const u16* W   = (z == 0) ? wq : (z == 1) ? wk : wv;
    const float* b = (z == 0) ? bq : (z == 1) ? bk : bv;
    u16* out       = (z == 0) ? Qb : (z == 1) ? Kb : Vb;
    gemm_body(A, W, b, out, (z == 2) ? 1 : 0);
}

__global__ __launch_bounds__(256) void gemm_one(
        const u16* __restrict__ A, const u16* __restrict__ W,
        const float* __restrict__ bias, void* __restrict__ out, int mode) {
    gemm_body(A, W, bias, out, mode);
}

// ---------- flash attention with bidirectional ALiBi ----------
// 1 wave per 16-query tile; 32-key tiles; Q,K in [B,H,S,D]; V transposed [B,H,D,S].
__global__ __launch_bounds__(256) void flash_kernel(
        const u16* __restrict__ Q, const u16* __restrict__ K,
        const u16* __restrict__ Vt, u16* __restrict__ AO) {
    __shared__ u16 Pl[4 * 16 * 32];     // per-wave 16x32 P tile (bf16)
    const int tid  = threadIdx.x;
    const int wv   = tid >> 6;
    const int lane = tid & 63;
    const int l16  = lane & 15;
    const int quad = lane >> 4;
    const int qt   = blockIdx.x * 4 + wv;   // 0..127
    const int bh   = blockIdx.y;            // 0..63
    const int h    = bh & (NHEAD - 1);
    const int b    = bh >> 4;
    const int q0   = qt * 16;
    const bool fwd = (h < 8);
    // slope = 24^(-(hm+1)/8)
    const float slope = exp2f(-(float)((h & 7) + 1) * (0.125f * 4.584962500721156f));
    const u16* Qb = Q + ((size_t)bh * S_LEN + q0) * HDIM;
    const u16* Kb = K + (size_t)bh * S_LEN * HDIM;
    const u16* Vb = Vt + (size_t)bh * HDIM * S_LEN;
    u16* Pw = &Pl[wv * 512];

    // Q A-fragments: A[m=l16][k=quad*8+j], d split 0..31 / 32..63
    bf16x8 aq0 = *(const bf16x8*)(Qb + l16 * HDIM + quad * 8);
    bf16x8 aq1 = *(const bf16x8*)(Qb + l16 * HDIM + 32 + quad * 8);

    f32x4 o[4];
#pragma unroll
    for (int dt = 0; dt < 4; dt++) o[dt] = {};
    float mrow[4] = {-1e30f, -1e30f, -1e30f, -1e30f};
    float lrow[4] = {0.f, 0.f, 0.f, 0.f};

    const int kt0 = fwd ? 0 : (q0 >> 5);
    const int kt1 = fwd ? ((q0 + 15) >> 5) : (S_LEN / 32 - 1);

    for (int kt = kt0; kt <= kt1; ++kt) {
        const int kb = kt * 32;
        f32x4 st[2];
#pragma unroll
        for (int t = 0; t < 2; t++) {
            const u16* kp = Kb + (size_t)(kb + t * 16 + l16) * HDIM + quad * 8;
            bf16x8 k0 = *(const bf16x8*)(kp);
            bf16x8 k1 = *(const bf16x8*)(kp + 32);
            f32x4 c = {};
            c = __builtin_amdgcn_mfma_f32_16x16x32_bf16(aq0, k0, c, 0, 0, 0);
            c = __builtin_amdgcn_mfma_f32_16x16x32_bf16(aq1, k1, c, 0, 0, 0);
            st[t] = c;
        }
        // scale + ALiBi bias + mask.  score row = quad*4+r (query), col = l16 (key)
        float p[2][4];
#pragma unroll
        for (int r = 0; r < 4; r++) {
            int qg = q0 + quad * 4 + r;
#pragma unroll
            for (int t = 0; t < 2; t++) {
                int kg = kb + t * 16 + l16;
                float sv = st[t][r] * 0.125f;
                if (fwd) sv += (kg <= qg) ? slope * (float)(kg - qg) : -1e9f;
                else     sv += (kg >= qg) ? slope * (float)(qg - kg) : -1e9f;
                p[t][r] = sv;
            }
        }
        // online softmax (reduce over 16 lanes of the quad = 16 keys x 2 tiles)
#pragma unroll
        for (int r = 0; r < 4; r++) {
            float vm = fmaxf(p[0][r], p[1][r]);
            vm = fmaxf(vm, __shfl_xor(vm, 1));
            vm = fmaxf(vm, __shfl_xor(vm, 2));
            vm = fmaxf(vm, __shfl_xor(vm, 4));
            vm = fmaxf(vm, __shfl_xor(vm, 8));
            float mnew  = fmaxf(mrow[r], vm);
            float alpha = __expf(mrow[r] - mnew);
            mrow[r] = mnew;
            float p0 = __expf(p[0][r] - mnew);
            float p1 = __expf(p[1][r] - mnew);
            p[0][r] = p0; p[1][r] = p1;
            float rs = p0 + p1;
            rs += __shfl_xor(rs, 1);
            rs += __shfl_xor(rs, 2);
            rs += __shfl_xor(rs, 4);
            rs += __shfl_xor(rs, 8);
            lrow[r] = lrow[r] * alpha + rs;
#pragma unroll
            for (int dt = 0; dt < 4; dt++) o[dt][r] *= alpha;
        }
        // P (C-layout) -> LDS -> A-operand layout
#pragma unroll
        for (int r = 0; r < 4; r++) {
            Pw[(quad * 4 + r) * 32 + l16]      = f2bf(p[0][r]);
            Pw[(quad * 4 + r) * 32 + 16 + l16] = f2bf(p[1][r]);
        }
        __builtin_amdgcn_s_waitcnt(0xC07F);   // lgkmcnt(0); wave-private LDS, no barrier
        bf16x8 pf = *(const bf16x8*)(&Pw[l16 * 32 + quad * 8]);
        // PV: B[k=key][n=d] from V^T rows (contiguous along key)
#pragma unroll
        for (int dt = 0; dt < 4; dt++) {
            bf16x8 vvf = *(const bf16x8*)(Vb + (size_t)(dt * 16 + l16) * S_LEN + kb + quad * 8);
            o[dt] = __builtin_amdgcn_mfma_f32_16x16x32_bf16(pf, vvf, o[dt], 0, 0, 0);
        }
    }
    // epilogue: AO[b, s, h*64+d] bf16
#pragma unroll
    for (int r = 0; r < 4; r++) {
        float inv = 1.0f / lrow[r];
        int qg = q0 + quad * 4 + r;
        u16* op = AO + ((size_t)b * S_LEN + qg) * DMODEL + h * HDIM;
#pragma unroll
        for (int dt = 0; dt < 4; dt++)
            op[dt * 16 + l16] = f2bf(o[dt][r] * inv);
    }
}

extern "C" void kernel_launch(void* const* d_in, const int* in_sizes, int n_in,
                              void* d_out, int out_size, void* d_ws, size_t ws_size,
                              hipStream_t stream) {
    const float* query = (const float*)d_in[0];
    const float* key   = (const float*)d_in[1];
    const float* value = (const float*)d_in[2];
    const float* Wq    = (const float*)d_in[3];
    const float* bq    = (const float*)d_in[4];
    const float* Wk    = (const float*)d_in[5];
    const float* bk    = (const float*)d_in[6];
    const float* Wv    = (const float*)d_in[7];
    const float* bv    = (const float*)d_in[8];
    const float* Wo    = (const float*)d_in[9];
    const float* bo    = (const float*)d_in[10];

    const size_t Xe = (size_t)MTOK * DMODEL;    // 8,388,608 elems
    const size_t We = (size_t)DMODEL * DMODEL;  // 1,048,576 elems
    u16* xq  = (u16*)d_ws;
    u16* xk  = xq + Xe;
    u16* xv  = xk + Xe;
    u16* wqb = xv + Xe;
    u16* wkb = wqb + We;
    u16* wvb = wkb + We;
    u16* wob = wvb + We;
    u16* Qb  = wob + We;
    u16* Kb  = Qb + Xe;
    u16* Vb  = Kb + Xe;   // transposed [B,H,D,S]
    u16* AO  = Vb + Xe;   // total ws use: 7*16MB + 4*2MB = 120 MB

    cast_kernel<<<dim3(Xe / 1024), dim3(256), 0, stream>>>(query, xq, (int)Xe);
    cast_kernel<<<dim3(Xe / 1024), dim3(256), 0, stream>>>(key,   xk, (int)Xe);
    cast_kernel<<<dim3(Xe / 1024), dim3(256), 0, stream>>>(value, xv, (int)Xe);
    cast_kernel<<<dim3(We / 1024), dim3(256), 0, stream>>>(Wq, wqb, (int)We);
    cast_kernel<<<dim3(We / 1024), dim3(256), 0, stream>>>(Wk, wkb, (int)We);
    cast_kernel<<<dim3(We / 1024), dim3(256), 0, stream>>>(Wv, wvb, (int)We);
    cast_kernel<<<dim3(We / 1024), dim3(256), 0, stream>>>(Wo, wob, (int)We);

    gemm_qkv<<<dim3(DMODEL / TN, MTOK / TM, 3), dim3(256), 0, stream>>>(
        xq, xk, xv, wqb, wkb, wvb, bq, bk, bv, Qb, Kb, Vb);

    flash_kernel<<<dim3(S_LEN / 16 / 4, NBATCH * NHEAD), dim3(256), 0, stream>>>(Qb, Kb, Vb, AO);

    gemm_one<<<dim3(DMODEL / TN, MTOK / TM, 1), dim3(256), 0, stream>>>(AO, wob, bo, d_out, 2);
}

// Round 2
// 588.346 us; speedup vs baseline: 1.0135x; 1.0135x over previous
//
#include <hip/hip_runtime.h>
#include <hip/hip_bf16.h>
#include <stdint.h>

typedef unsigned short u16;
typedef __attribute__((ext_vector_type(8))) __bf16 bf16x8;
typedef __attribute__((ext_vector_type(4))) float f32x4;
typedef __attribute__((ext_vector_type(4))) unsigned int u32x4;

#define S_LEN 2048
#define NHEAD 16
#define HDIM 64
#define DMODEL 1024
#define NBATCH 4
#define MTOK (NBATCH * S_LEN)   // 8192

// ---------- helpers ----------
__device__ __forceinline__ u16 f2bf(float f) {
    uint32_t u = __float_as_uint(f);
    u += 0x7fffu + ((u >> 16) & 1u);   // RNE
    return (u16)(u >> 16);
}

__device__ __forceinline__ uint32_t f2bf2(float a, float b) {
    __hip_bfloat162 h = __float22bfloat162_rn(make_float2(a, b));
    return *(uint32_t*)&h;   // low 16 = a, high 16 = b
}

// async global->LDS, 16B per lane; lds dest must be wave-uniform base (+lane*16)
__device__ __forceinline__ void gld_lds16(const u16* g, u16* l) {
    __builtin_amdgcn_global_load_lds(
        (const __attribute__((address_space(1))) void*)g,
        (__attribute__((address_space(3))) void*)l, 16, 0, 0);
}

// ---------- fp32 -> bf16 cast ----------
__global__ void cast_kernel(const float* __restrict__ src, u16* __restrict__ dst, int n) {
    int i = (blockIdx.x * 256 + threadIdx.x) * 4;
    if (i + 3 < n) {
        float4 v = *(const float4*)(src + i);
        ushort4 o;
        o.x = f2bf(v.x); o.y = f2bf(v.y); o.z = f2bf(v.z); o.w = f2bf(v.w);
        *(ushort4*)(dst + i) = o;
    }
}

// ---------- GEMM: out[m,n] = sum_k A[m,k]*W[n,k] + bias[n] ----------
// mode 0: bf16 out, [B,H,S,D] layout (Q/K)
// mode 1: bf16 out, [B,H,D,S] layout (V transposed)
// mode 2: fp32 out, row-major [m,n] (final projection)
#define TM 128
#define TN 128

__device__ __forceinline__ void gemm_body(const u16* __restrict__ A,
                                          const u16* __restrict__ W,
                                          const float* __restrict__ bias,
                                          void* __restrict__ outp, int mode) {
    // m97 structure: unpadded [128][32] tiles, global_load_lds width=16
    __shared__ __align__(16) u16 As[TM * 32];
    __shared__ __align__(16) u16 Bs[TN * 32];
    const int tid  = threadIdx.x;
    const int lane = tid & 63;
    const int wv   = tid >> 6;
    const int l16  = lane & 15;
    const int quad = lane >> 4;
    const int wm   = (wv >> 1) * 64;
    const int wn   = (wv & 1) * 64;
    const int m0   = blockIdx.y * TM;
    const int n0   = blockIdx.x * TN;

    f32x4 acc[4][4];
#pragma unroll
    for (int i = 0; i < 4; i++)
#pragma unroll
        for (int j = 0; j < 4; j++) acc[i][j] = {};

    // staging geometry: lane writes LDS elem (wv*512 + lane*8) -> row wv*16+lane/4, col8 = lane&3
    const int arow = wv * 16 + (lane >> 2);
    const int acol = (lane & 3) * 8;
    const u16* gA = A + (size_t)(m0 + arow) * DMODEL + acol;
    const u16* gB = W + (size_t)(n0 + arow) * DMODEL + acol;
    u16* lA = As + wv * 16 * 32;   // wave-uniform
    u16* lB = Bs + wv * 16 * 32;

    for (int kb = 0; kb < DMODEL; kb += 32) {
        gld_lds16(gA + kb, lA);
        gld_lds16(gA + kb + (size_t)64 * DMODEL, lA + 64 * 32);
        gld_lds16(gB + kb, lB);
        gld_lds16(gB + kb + (size_t)64 * DMODEL, lB + 64 * 32);
        __builtin_amdgcn_s_waitcnt(0x0F70);   // vmcnt(0)
        __syncthreads();

        bf16x8 af[4], bfv[4];
#pragma unroll
        for (int i = 0; i < 4; i++)
            af[i] = *(const bf16x8*)(&As[(wm + i * 16 + l16) * 32 + quad * 8]);
#pragma unroll
        for (int j = 0; j < 4; j++)
            bfv[j] = *(const bf16x8*)(&Bs[(wn + j * 16 + l16) * 32 + quad * 8]);
#pragma unroll
        for (int i = 0; i < 4; i++)
#pragma unroll
            for (int j = 0; j < 4; j++)
                acc[i][j] = __builtin_amdgcn_mfma_f32_16x16x32_bf16(af[i], bfv[j], acc[i][j], 0, 0, 0);
        __syncthreads();
    }

    // epilogue: C row = quad*4+r, col = l16 within each 16x16 tile
#pragma unroll
    for (int j = 0; j < 4; j++) {
        int n = n0 + wn + j * 16 + l16;
        float bv = bias[n];
#pragma unroll
        for (int i = 0; i < 4; i++) {
            int mbase = m0 + wm + i * 16 + quad * 4;
#pragma unroll
            for (int r = 0; r < 4; r++) {
                int m = mbase + r;
                float v = acc[i][j][r] + bv;
                if (mode == 2) {
                    ((float*)outp)[(size_t)m * DMODEL + n] = v;
                } else {
                    int b = m >> 11, s = m & (S_LEN - 1);
                    int h = n >> 6, d = n & 63;
                    u16* o = (u16*)outp;
                    size_t idx = (mode == 0)
                        ? ((((size_t)(b * NHEAD + h)) * S_LEN + s) * HDIM + d)
                        : ((((size_t)(b * NHEAD + h)) * HDIM + d) * S_LEN + s);
                    o[idx] = f2bf(v);
                }
            }
        }
    }
}

__global__ __launch_bounds__(256) void gemm_qkv(
        const u16* __restrict__ xq, const u16* __restrict__ xk, const u16* __restrict__ xv,
        const u16* __restrict__ wq, const u16* __restrict__ wk, const u16* __restrict__ wv,
        const float* __restrict__ bq, const float* __restrict__ bk, const float* __restrict__ bv,
        u16* __restrict__ Qb, u16* __restrict__ Kb, u16* __restrict__ Vb) {
    int z = blockIdx.z;
    const u16* A   = (z == 0) ? xq : (z == 1) ? xk : xv;
    const u16* W   = (z == 0) ? wq : (z == 1) ? wk : wv;
    const float* b = (z == 0) ? bq : (z == 1) ? bk : bv;
    u16* out       = (z == 0) ? Qb : (z == 1) ? Kb : Vb;
    gemm_body(A, W, b, out, (z == 2) ? 1 : 0);
}

__global__ __launch_bounds__(256) void gemm_one(
        const u16* __restrict__ A, const u16* __restrict__ W,
        const float* __restrict__ bias, void* __restrict__ out, int mode) {
    gemm_body(A, W, bias, out, mode);
}

// ---------- flash attention, bidirectional ALiBi, fixed-max softmax ----------
// wave handles q-tiles {qt, 127-qt} sequentially -> every wave does exactly 33
// 64-key tile iterations (load-balanced). Row sums via ones-operand MFMA.
#define PLDP 72   // P row stride in u16: 64 + 8 pad (2-way bank aliasing max)

__global__ __launch_bounds__(256) void flash_kernel(
        const u16* __restrict__ Q, const u16* __restrict__ K,
        const u16* __restrict__ Vt, u16* __restrict__ AO) {
    __shared__ __align__(16) u16 Pl[4][16 * PLDP];
    const int tid  = threadIdx.x;
    const int wv   = tid >> 6;
    const int lane = tid & 63;
    const int l16  = lane & 15;
    const int quad = lane >> 4;
    const int qt_a = blockIdx.x * 4 + wv;   // 0..63
    const int bh   = blockIdx.y;            // 0..63
    const int h    = bh & (NHEAD - 1);
    const int b    = bh >> 4;
    const bool fwd = (h < 8);
    const int sgn  = fwd ? 1 : -1;
    // slope2 = 24^(-(hm+1)/8) * log2(e)
    const float slope2 = exp2f(-(float)((h & 7) + 1) * 0.5731203125901445f) * 1.4426950408889634f;
    const float cL = 0.18033688011112042f;   // log2(e)/8

    const u16* Kb = K + (size_t)bh * S_LEN * HDIM;
    const u16* Vb = Vt + (size_t)bh * HDIM * S_LEN;
    u16* Pw = &Pl[wv][0];

    // per-(t,r) bias base: slope2*sgn*((16t+l16) - (quad*4+r)) - 16  (fixed max M2=16 folded)
    float brt[4][4];
#pragma unroll
    for (int t = 0; t < 4; t++)
#pragma unroll
        for (int r = 0; r < 4; r++)
            brt[t][r] = slope2 * (float)(sgn * (16 * t + l16 - (quad * 4 + r))) - 16.0f;

    bf16x8 ones;
#pragma unroll
    for (int j = 0; j < 8; j++) ones[j] = (__bf16)1.0f;

#pragma unroll 1
    for (int half = 0; half < 2; half++) {
        const int qt = half ? (127 - qt_a) : qt_a;
        const int q0 = qt * 16;
        const u16* Qp = Q + ((size_t)bh * S_LEN + q0) * HDIM;
        bf16x8 aq0 = *(const bf16x8*)(Qp + l16 * HDIM + quad * 8);
        bf16x8 aq1 = *(const bf16x8*)(Qp + l16 * HDIM + 32 + quad * 8);

        f32x4 o[4], osum = {};
#pragma unroll
        for (int dt = 0; dt < 4; dt++) o[dt] = {};

        const int m   = q0 >> 6;              // diagonal tile index
        const int kt0 = fwd ? 0 : m;
        const int kt1 = fwd ? m : (S_LEN / 64 - 1);

        for (int kt = kt0; kt <= kt1; ++kt) {
            const int kb = kt * 64;
            // QK^T for 4 key sub-tiles of 16
            f32x4 st[4];
#pragma unroll
            for (int t = 0; t < 4; t++) {
                const u16* kp = Kb + (size_t)(kb + t * 16 + l16) * HDIM + quad * 8;
                bf16x8 k0 = *(const bf16x8*)(kp);
                bf16x8 k1 = *(const bf16x8*)(kp + 32);
                f32x4 c = {};
                c = __builtin_amdgcn_mfma_f32_16x16x32_bf16(aq0, k0, c, 0, 0, 0);
                c = __builtin_amdgcn_mfma_f32_16x16x32_bf16(aq1, k1, c, 0, 0, 0);
                st[t] = c;
            }
            // V fragments (independent of softmax -> issue early)
            bf16x8 v0[4], v1[4];
#pragma unroll
            for (int dt = 0; dt < 4; dt++) {
                const u16* vp = Vb + (size_t)(dt * 16 + l16) * S_LEN + kb + quad * 8;
                v0[dt] = *(const bf16x8*)(vp);
                v1[dt] = *(const bf16x8*)(vp + 32);
            }

            const float kq = slope2 * (float)(sgn * (kb - q0));
            float p[4][4];
            if (kt == m) {   // boundary (diagonal) tile: explicit integer mask
#pragma unroll
                for (int r = 0; r < 4; r++) {
                    const int qg = q0 + quad * 4 + r;
#pragma unroll
                    for (int t = 0; t < 4; t++) {
                        const int kg = kb + 16 * t + l16;
                        const bool ok = fwd ? (kg <= qg) : (kg >= qg);
                        float s2 = fmaf(st[t][r], cL, brt[t][r] + kq);
                        p[t][r] = ok ? exp2f(s2) : 0.0f;
                    }
                }
            } else {         // interior tile: no masking
#pragma unroll
                for (int r = 0; r < 4; r++)
#pragma unroll
                    for (int t = 0; t < 4; t++)
                        p[t][r] = exp2f(fmaf(st[t][r], cL, brt[t][r] + kq));
            }
            // P (C-layout) -> LDS -> A-operand layout, packed bf16 conversion
#pragma unroll
            for (int r = 0; r < 4; r++) {
                uint32_t w01 = f2bf2(p[0][r], p[1][r]);
                uint32_t w23 = f2bf2(p[2][r], p[3][r]);
                u16* rp = Pw + (quad * 4 + r) * PLDP + l16;
                rp[0]  = (u16)w01;
                rp[16] = (u16)(w01 >> 16);
                rp[32] = (u16)w23;
                rp[48] = (u16)(w23 >> 16);
            }
            __builtin_amdgcn_s_waitcnt(0xC07F);   // lgkmcnt(0); wave-private LDS
            bf16x8 pf0 = *(const bf16x8*)(&Pw[l16 * PLDP + quad * 8]);
            bf16x8 pf1 = *(const bf16x8*)(&Pw[l16 * PLDP + 32 + quad * 8]);
#pragma unroll
            for (int dt = 0; dt < 4; dt++) {
                o[dt] = __builtin_amdgcn_mfma_f32_16x16x32_bf16(pf0, v0[dt], o[dt], 0, 0, 0);
                o[dt] = __builtin_amdgcn_mfma_f32_16x16x32_bf16(pf1, v1[dt], o[dt], 0, 0, 0);
            }
            osum = __builtin_amdgcn_mfma_f32_16x16x32_bf16(pf0, ones, osum, 0, 0, 0);
            osum = __builtin_amdgcn_mfma_f32_16x16x32_bf16(pf1, ones, osum, 0, 0, 0);
        }
        // epilogue: AO[b, s, h*64+d] bf16
#pragma unroll
        for (int r = 0; r < 4; r++) {
            float inv = 1.0f / osum[r];
            int qg = q0 + quad * 4 + r;
            u16* op = AO + ((size_t)b * S_LEN + qg) * DMODEL + h * HDIM;
#pragma unroll
            for (int dt = 0; dt < 4; dt++)
                op[dt * 16 + l16] = f2bf(o[dt][r] * inv);
        }
    }
}

extern "C" void kernel_launch(void* const* d_in, const int* in_sizes, int n_in,
                              void* d_out, int out_size, void* d_ws, size_t ws_size,
                              hipStream_t stream) {
    const float* query = (const float*)d_in[0];
    const float* key   = (const float*)d_in[1];
    const float* value = (const float*)d_in[2];
    const float* Wq    = (const float*)d_in[3];
    const float* bq    = (const float*)d_in[4];
    const float* Wk    = (const float*)d_in[5];
    const float* bk    = (const float*)d_in[6];
    const float* Wv    = (const float*)d_in[7];
    const float* bv    = (const float*)d_in[8];
    const float* Wo    = (const float*)d_in[9];
    const float* bo    = (const float*)d_in[10];

    const size_t Xe = (size_t)MTOK * DMODEL;    // 8,388,608 elems
    const size_t We = (size_t)DMODEL * DMODEL;  // 1,048,576 elems
    u16* xq  = (u16*)d_ws;
    u16* xk  = xq + Xe;
    u16* xv  = xk + Xe;
    u16* wqb = xv + Xe;
    u16* wkb = wqb + We;
    u16* wvb = wkb + We;
    u16* wob = wvb + We;
    u16* Qb  = wob + We;
    u16* Kb  = Qb + Xe;
    u16* Vb  = Kb + Xe;   // transposed [B,H,D,S]
    u16* AO  = Vb + Xe;   // total ws use: 7*16MB + 8MB = 120 MB

    cast_kernel<<<dim3(Xe / 1024), dim3(256), 0, stream>>>(query, xq, (int)Xe);
    cast_kernel<<<dim3(Xe / 1024), dim3(256), 0, stream>>>(key,   xk, (int)Xe);
    cast_kernel<<<dim3(Xe / 1024), dim3(256), 0, stream>>>(value, xv, (int)Xe);
    cast_kernel<<<dim3(We / 1024), dim3(256), 0, stream>>>(Wq, wqb, (int)We);
    cast_kernel<<<dim3(We / 1024), dim3(256), 0, stream>>>(Wk, wkb, (int)We);
    cast_kernel<<<dim3(We / 1024), dim3(256), 0, stream>>>(Wv, wvb, (int)We);
    cast_kernel<<<dim3(We / 1024), dim3(256), 0, stream>>>(Wo, wob, (int)We);

    gemm_qkv<<<dim3(DMODEL / TN, MTOK / TM, 3), dim3(256), 0, stream>>>(
        xq, xk, xv, wqb, wkb, wvb, bq, bk, bv, Qb, Kb, Vb);

    flash_kernel<<<dim3(16, NBATCH * NHEAD), dim3(256), 0, stream>>>(Qb, Kb, Vb, AO);

    gemm_one<<<dim3(DMODEL / TN, MTOK / TM, 1), dim3(256), 0, stream>>>(AO, wob, bo, d_out, 2);
}

// Round 3
// 402.059 us; speedup vs baseline: 1.4831x; 1.4633x over previous
//
#include <hip/hip_runtime.h>
#include <hip/hip_bf16.h>
#include <stdint.h>

typedef unsigned short u16;
typedef __attribute__((ext_vector_type(8))) __bf16 bf16x8;
typedef __attribute__((ext_vector_type(4))) float f32x4;
typedef __attribute__((ext_vector_type(4))) unsigned int u32x4;

#define S_LEN 2048
#define NHEAD 16
#define HDIM 64
#define DMODEL 1024
#define NBATCH 4
#define MTOK (NBATCH * S_LEN)   // 8192

// ---------- helpers ----------
__device__ __forceinline__ u16 f2bf(float f) {
    uint32_t u = __float_as_uint(f);
    u += 0x7fffu + ((u >> 16) & 1u);   // RNE
    return (u16)(u >> 16);
}

// async global->LDS, 16B per lane; lds dest must be wave-uniform base (+lane*16)
__device__ __forceinline__ void gld_lds16(const u16* g, u16* l) {
    __builtin_amdgcn_global_load_lds(
        (const __attribute__((address_space(1))) void*)g,
        (__attribute__((address_space(3))) void*)l, 16, 0, 0);
}

// ---------- fp32 -> bf16 cast ----------
__global__ void cast_kernel(const float* __restrict__ src, u16* __restrict__ dst, int n) {
    int i = (blockIdx.x * 256 + threadIdx.x) * 4;
    if (i + 3 < n) {
        float4 v = *(const float4*)(src + i);
        ushort4 o;
        o.x = f2bf(v.x); o.y = f2bf(v.y); o.z = f2bf(v.z); o.w = f2bf(v.w);
        *(ushort4*)(dst + i) = o;
    }
}

// ---------- GEMM: out[m,n] = sum_k A[m,k]*W[n,k] + bias[n] ----------
#define TM 128
#define TN 128

__device__ __forceinline__ void gemm_body(const u16* __restrict__ A,
                                          const u16* __restrict__ W,
                                          const float* __restrict__ bias,
                                          void* __restrict__ outp, int mode) {
    __shared__ __align__(16) u16 As[TM * 32];
    __shared__ __align__(16) u16 Bs[TN * 32];
    const int tid  = threadIdx.x;
    const int lane = tid & 63;
    const int wv   = tid >> 6;
    const int l16  = lane & 15;
    const int quad = lane >> 4;
    const int wm   = (wv >> 1) * 64;
    const int wn   = (wv & 1) * 64;
    const int m0   = blockIdx.y * TM;
    const int n0   = blockIdx.x * TN;

    f32x4 acc[4][4];
#pragma unroll
    for (int i = 0; i < 4; i++)
#pragma unroll
        for (int j = 0; j < 4; j++) acc[i][j] = {};

    const int arow = wv * 16 + (lane >> 2);
    const int acol = (lane & 3) * 8;
    const u16* gA = A + (size_t)(m0 + arow) * DMODEL + acol;
    const u16* gB = W + (size_t)(n0 + arow) * DMODEL + acol;
    u16* lA = As + wv * 16 * 32;   // wave-uniform
    u16* lB = Bs + wv * 16 * 32;

    for (int kb = 0; kb < DMODEL; kb += 32) {
        gld_lds16(gA + kb, lA);
        gld_lds16(gA + kb + (size_t)64 * DMODEL, lA + 64 * 32);
        gld_lds16(gB + kb, lB);
        gld_lds16(gB + kb + (size_t)64 * DMODEL, lB + 64 * 32);
        __builtin_amdgcn_s_waitcnt(0x0F70);   // vmcnt(0)
        __syncthreads();

        bf16x8 af[4], bfv[4];
#pragma unroll
        for (int i = 0; i < 4; i++)
            af[i] = *(const bf16x8*)(&As[(wm + i * 16 + l16) * 32 + quad * 8]);
#pragma unroll
        for (int j = 0; j < 4; j++)
            bfv[j] = *(const bf16x8*)(&Bs[(wn + j * 16 + l16) * 32 + quad * 8]);
#pragma unroll
        for (int i = 0; i < 4; i++)
#pragma unroll
            for (int j = 0; j < 4; j++)
                acc[i][j] = __builtin_amdgcn_mfma_f32_16x16x32_bf16(af[i], bfv[j], acc[i][j], 0, 0, 0);
        __syncthreads();
    }

#pragma unroll
    for (int j = 0; j < 4; j++) {
        int n = n0 + wn + j * 16 + l16;
        float bv = bias[n];
#pragma unroll
        for (int i = 0; i < 4; i++) {
            int mbase = m0 + wm + i * 16 + quad * 4;
#pragma unroll
            for (int r = 0; r < 4; r++) {
                int m = mbase + r;
                float v = acc[i][j][r] + bv;
                if (mode == 2) {
                    ((float*)outp)[(size_t)m * DMODEL + n] = v;
                } else {
                    int b = m >> 11, s = m & (S_LEN - 1);
                    int h = n >> 6, d = n & 63;
                    u16* o = (u16*)outp;
                    size_t idx = (mode == 0)
                        ? ((((size_t)(b * NHEAD + h)) * S_LEN + s) * HDIM + d)
                        : ((((size_t)(b * NHEAD + h)) * HDIM + d) * S_LEN + s);
                    o[idx] = f2bf(v);
                }
            }
        }
    }
}

__global__ __launch_bounds__(256) void gemm_qkv(
        const u16* __restrict__ xq, const u16* __restrict__ xk, const u16* __restrict__ xv,
        const u16* __restrict__ wq, const u16* __restrict__ wk, const u16* __restrict__ wv,
        const float* __restrict__ bq, const float* __restrict__ bk, const float* __restrict__ bv,
        u16* __restrict__ Qb, u16* __restrict__ Kb, u16* __restrict__ Vb) {
    int z = blockIdx.z;
    const u16* A   = (z == 0) ? xq : (z == 1) ? xk : xv;
    const u16* W   = (z == 0) ? wq : (z == 1) ? wk : wv;
    const float* b = (z == 0) ? bq : (z == 1) ? bk : bv;
    u16* out       = (z == 0) ? Qb : (z == 1) ? Kb : Vb;
    gemm_body(A, W, b, out, (z == 2) ? 1 : 0);
}

__global__ __launch_bounds__(256) void gemm_one(
        const u16* __restrict__ A, const u16* __restrict__ W,
        const float* __restrict__ bias, void* __restrict__ out, int mode) {
    gemm_body(A, W, bias, out, mode);
}

// ---------- flash attention v3: block-cooperative LDS K/V, XOR swizzle ----------
// Block = 4 waves = one 64-query group; all waves share the same K-tile range
// (diag tile == group for fwd and bwd). Groups paired {g, 31-g} -> 33 iters/block.
// LDS layout: rows of 64 bf16 (128 B); col16 index XOR-swizzled by (row&7) so
// both global_load_lds (no padding allowed) and b128 fragment reads are
// conflict-free. Total LDS = 16+16+8 = 40 KB -> 4 blocks/CU.
__global__ __launch_bounds__(256, 4) void flash_kernel(
        const u16* __restrict__ Q, const u16* __restrict__ K,
        const u16* __restrict__ Vt, u16* __restrict__ AO) {
    __shared__ __align__(16) u16 Ksm[2][64 * 64];
    __shared__ __align__(16) u16 Vsm[2][64 * 64];
    __shared__ __align__(16) u16 Psm[4][16 * 64];

    const int tid  = threadIdx.x;
    const int wv   = tid >> 6;
    const int lane = tid & 63;
    const int l16  = lane & 15;
    const int quad = lane >> 4;

    // XCD-pinning swizzle: all 16 blocks of a bh share (linear id % 8)
    const int lid   = blockIdx.x + 16 * blockIdx.y;   // 0..1023
    const int xcd   = lid & 7;
    const int slot  = lid >> 3;                        // 0..127
    const int bh    = xcd + 8 * (slot >> 4);           // 0..63
    const int g_idx = slot & 15;                       // 0..15

    const int h    = bh & (NHEAD - 1);
    const int b    = bh >> 4;
    const bool fwd = (h < 8);
    const int sgn  = fwd ? 1 : -1;
    const float slope2 = exp2f(-(float)((h & 7) + 1) * 0.5731203125901445f) * 1.4426950408889634f;
    const float cL = 0.18033688011112042f;   // log2(e)/8

    const u16* Kg = K + (size_t)bh * S_LEN * HDIM;
    const u16* Vg = Vt + (size_t)bh * HDIM * S_LEN;

    // staging lane constants: 8 lanes per row, col16 = (lane&7) ^ (lane>>3)
    const int sr = lane >> 3;
    const int sc = (lane & 7) ^ sr;
    const int r0 = 16 * wv;          // this wave stages rows r0..r0+15

    // fragment-read swizzled col16
    const int cA = quad ^ (l16 & 7);          // global col16 = quad
    const int cB = (quad + 4) ^ (l16 & 7);    // global col16 = quad+4

    // ALiBi per-(t,r) in-tile offset, fixed max 16 folded
    float brt[4][4];
#pragma unroll
    for (int t = 0; t < 4; t++)
#pragma unroll
        for (int r = 0; r < 4; r++)
            brt[t][r] = slope2 * (float)(sgn * (16 * t + l16 - (quad * 4 + r))) - 16.0f;

    bf16x8 ones;
#pragma unroll
    for (int j = 0; j < 8; j++) ones[j] = (__bf16)1.0f;

#pragma unroll 1
    for (int half = 0; half < 2; half++) {
        const int g  = half ? (31 - g_idx) : g_idx;    // 64-query group 0..31
        const int q0 = g * 64 + wv * 16;
        const u16* Qp = Q + ((size_t)bh * S_LEN + q0) * HDIM;
        const bf16x8 aq0 = *(const bf16x8*)(Qp + l16 * HDIM + quad * 8);
        const bf16x8 aq1 = *(const bf16x8*)(Qp + l16 * HDIM + 32 + quad * 8);

        f32x4 o[4], osum = {};
#pragma unroll
        for (int dt = 0; dt < 4; dt++) o[dt] = {};

        const int kt0 = fwd ? 0 : g;
        const int kt1 = fwd ? g : (S_LEN / 64 - 1);

        __syncthreads();   // protect LDS buffers from previous half's readers
        // preload first tile into buf 0
        {
            const int kb = kt0 * 64;
            gld_lds16(Kg + (size_t)(kb + r0 + sr) * 64 + sc * 8,     &Ksm[0][r0 * 64]);
            gld_lds16(Kg + (size_t)(kb + r0 + 8 + sr) * 64 + sc * 8, &Ksm[0][(r0 + 8) * 64]);
            gld_lds16(Vg + (size_t)(r0 + sr) * S_LEN + kb + sc * 8,     &Vsm[0][r0 * 64]);
            gld_lds16(Vg + (size_t)(r0 + 8 + sr) * S_LEN + kb + sc * 8, &Vsm[0][(r0 + 8) * 64]);
        }

        int buf = 0;
        for (int kt = kt0; kt <= kt1; ++kt) {
            __builtin_amdgcn_s_waitcnt(0x0F70);   // vmcnt(0): buf staged
            __syncthreads();
            if (kt < kt1) {   // stage next tile into the other buffer
                const int kb = (kt + 1) * 64;
                gld_lds16(Kg + (size_t)(kb + r0 + sr) * 64 + sc * 8,     &Ksm[buf ^ 1][r0 * 64]);
                gld_lds16(Kg + (size_t)(kb + r0 + 8 + sr) * 64 + sc * 8, &Ksm[buf ^ 1][(r0 + 8) * 64]);
                gld_lds16(Vg + (size_t)(r0 + sr) * S_LEN + kb + sc * 8,     &Vsm[buf ^ 1][r0 * 64]);
                gld_lds16(Vg + (size_t)(r0 + 8 + sr) * S_LEN + kb + sc * 8, &Vsm[buf ^ 1][(r0 + 8) * 64]);
            }
            const int kb = kt * 64;
            const u16* Ks = &Ksm[buf][0];
            const u16* Vs = &Vsm[buf][0];

            // QK^T from LDS
            f32x4 st[4];
#pragma unroll
            for (int t = 0; t < 4; t++) {
                const u16* kp = Ks + (16 * t + l16) * 64;
                bf16x8 k0 = *(const bf16x8*)(kp + cA * 8);
                bf16x8 k1 = *(const bf16x8*)(kp + cB * 8);
                f32x4 c = {};
                c = __builtin_amdgcn_mfma_f32_16x16x32_bf16(aq0, k0, c, 0, 0, 0);
                c = __builtin_amdgcn_mfma_f32_16x16x32_bf16(aq1, k1, c, 0, 0, 0);
                st[t] = c;
            }

            const float kq = slope2 * (float)(sgn * (kb - q0));
            float p[4][4];
            if (kt == g) {   // diagonal tile: explicit mask
#pragma unroll
                for (int r = 0; r < 4; r++) {
                    const int qg = q0 + quad * 4 + r;
#pragma unroll
                    for (int t = 0; t < 4; t++) {
                        const int kg = kb + 16 * t + l16;
                        const bool ok = fwd ? (kg <= qg) : (kg >= qg);
                        float s2 = fmaf(st[t][r], cL, brt[t][r] + kq);
                        p[t][r] = ok ? exp2f(s2) : 0.0f;
                    }
                }
            } else {
#pragma unroll
                for (int r = 0; r < 4; r++)
#pragma unroll
                    for (int t = 0; t < 4; t++)
                        p[t][r] = exp2f(fmaf(st[t][r], cL, brt[t][r] + kq));
            }

            // P (C-layout) -> swizzled LDS -> A-operand layout (wave-private)
            u16* Pw = &Psm[wv][0];
#pragma unroll
            for (int r = 0; r < 4; r++) {
                const int prow = quad * 4 + r;
                const int pr7  = prow & 7;
#pragma unroll
                for (int t = 0; t < 4; t++) {
                    const int c16 = (2 * t + (l16 >> 3)) ^ pr7;
                    Pw[prow * 64 + c16 * 8 + (l16 & 7)] = f2bf(p[t][r]);
                }
            }
            __builtin_amdgcn_s_waitcnt(0xC07F);   // lgkmcnt(0); wave-private
            bf16x8 pf0 = *(const bf16x8*)(&Pw[l16 * 64 + cA * 8]);
            bf16x8 pf1 = *(const bf16x8*)(&Pw[l16 * 64 + cB * 8]);

            // PV from LDS V
#pragma unroll
            for (int dt = 0; dt < 4; dt++) {
                const u16* vp = Vs + (dt * 16 + l16) * 64;
                bf16x8 v0 = *(const bf16x8*)(vp + cA * 8);
                bf16x8 v1 = *(const bf16x8*)(vp + cB * 8);
                o[dt] = __builtin_amdgcn_mfma_f32_16x16x32_bf16(pf0, v0, o[dt], 0, 0, 0);
                o[dt] = __builtin_amdgcn_mfma_f32_16x16x32_bf16(pf1, v1, o[dt], 0, 0, 0);
            }
            osum = __builtin_amdgcn_mfma_f32_16x16x32_bf16(pf0, ones, osum, 0, 0, 0);
            osum = __builtin_amdgcn_mfma_f32_16x16x32_bf16(pf1, ones, osum, 0, 0, 0);
            buf ^= 1;
        }

        // epilogue: AO[b, s, h*64+d] bf16
#pragma unroll
        for (int r = 0; r < 4; r++) {
            float inv = 1.0f / osum[r];
            int qg = q0 + quad * 4 + r;
            u16* op = AO + ((size_t)b * S_LEN + qg) * DMODEL + h * HDIM;
#pragma unroll
            for (int dt = 0; dt < 4; dt++)
                op[dt * 16 + l16] = f2bf(o[dt][r] * inv);
        }
    }
}

extern "C" void kernel_launch(void* const* d_in, const int* in_sizes, int n_in,
                              void* d_out, int out_size, void* d_ws, size_t ws_size,
                              hipStream_t stream) {
    const float* query = (const float*)d_in[0];
    const float* key   = (const float*)d_in[1];
    const float* value = (const float*)d_in[2];
    const float* Wq    = (const float*)d_in[3];
    const float* bq    = (const float*)d_in[4];
    const float* Wk    = (const float*)d_in[5];
    const float* bk    = (const float*)d_in[6];
    const float* Wv    = (const float*)d_in[7];
    const float* bv    = (const float*)d_in[8];
    const float* Wo    = (const float*)d_in[9];
    const float* bo    = (const float*)d_in[10];

    const size_t Xe = (size_t)MTOK * DMODEL;    // 8,388,608 elems
    const size_t We = (size_t)DMODEL * DMODEL;  // 1,048,576 elems
    u16* xq  = (u16*)d_ws;
    u16* xk  = xq + Xe;
    u16* xv  = xk + Xe;
    u16* wqb = xv + Xe;
    u16* wkb = wqb + We;
    u16* wvb = wkb + We;
    u16* wob = wvb + We;
    u16* Qb  = wob + We;
    u16* Kb  = Qb + Xe;
    u16* Vb  = Kb + Xe;   // transposed [B,H,D,S]
    u16* AO  = Vb + Xe;

    cast_kernel<<<dim3(Xe / 1024), dim3(256), 0, stream>>>(query, xq, (int)Xe);
    cast_kernel<<<dim3(Xe / 1024), dim3(256), 0, stream>>>(key,   xk, (int)Xe);
    cast_kernel<<<dim3(Xe / 1024), dim3(256), 0, stream>>>(value, xv, (int)Xe);
    cast_kernel<<<dim3(We / 1024), dim3(256), 0, stream>>>(Wq, wqb, (int)We);
    cast_kernel<<<dim3(We / 1024), dim3(256), 0, stream>>>(Wk, wkb, (int)We);
    cast_kernel<<<dim3(We / 1024), dim3(256), 0, stream>>>(Wv, wvb, (int)We);
    cast_kernel<<<dim3(We / 1024), dim3(256), 0, stream>>>(Wo, wob, (int)We);

    gemm_qkv<<<dim3(DMODEL / TN, MTOK / TM, 3), dim3(256), 0, stream>>>(
        xq, xk, xv, wqb, wkb, wvb, bq, bk, bv, Qb, Kb, Vb);

    flash_kernel<<<dim3(16, NBATCH * NHEAD), dim3(256), 0, stream>>>(Qb, Kb, Vb, AO);

    gemm_one<<<dim3(DMODEL / TN, MTOK / TM, 1), dim3(256), 0, stream>>>(AO, wob, bo, d_out, 2);
}

// Round 4
// 334.872 us; speedup vs baseline: 1.7807x; 1.2006x over previous
//
#include <hip/hip_runtime.h>
#include <hip/hip_bf16.h>
#include <stdint.h>

typedef unsigned short u16;
typedef __attribute__((ext_vector_type(8))) __bf16 bf16x8;
typedef __attribute__((ext_vector_type(4))) float f32x4;
typedef __attribute__((ext_vector_type(4))) unsigned int u32x4;

#define S_LEN 2048
#define NHEAD 16
#define HDIM 64
#define DMODEL 1024
#define NBATCH 4
#define MTOK (NBATCH * S_LEN)   // 8192

// ---------- helpers ----------
__device__ __forceinline__ u16 f2bf(float f) {
    uint32_t u = __float_as_uint(f);
    u += 0x7fffu + ((u >> 16) & 1u);   // RNE
    return (u16)(u >> 16);
}

// async global->LDS, 16B per lane; lds dest must be wave-uniform base (+lane*16)
__device__ __forceinline__ void gld_lds16(const u16* g, u16* l) {
    __builtin_amdgcn_global_load_lds(
        (const __attribute__((address_space(1))) void*)g,
        (__attribute__((address_space(3))) void*)l, 16, 0, 0);
}

// ---------- fused fp32 -> bf16 cast: all 7 tensors in one launch ----------
// layout: 3 x-tensors of 2^23 elems (2^21 float4) then 4 W of 2^20 (2^18 float4).
// region boundaries are multiples of 256 -> whole blocks are region-uniform.
__global__ __launch_bounds__(256) void cast_all(
        const float* __restrict__ q, const float* __restrict__ k, const float* __restrict__ v,
        const float* __restrict__ wq, const float* __restrict__ wk,
        const float* __restrict__ wv, const float* __restrict__ wo,
        u16* __restrict__ xq, u16* __restrict__ xk, u16* __restrict__ xv,
        u16* __restrict__ wqb, u16* __restrict__ wkb, u16* __restrict__ wvb,
        u16* __restrict__ wob) {
    size_t idx4 = (size_t)blockIdx.x * 256 + threadIdx.x;   // float4 index
    const float* src;
    u16* dst;
    size_t off;
    if (idx4 < (size_t)3 << 21) {
        int t = (int)(idx4 >> 21);
        off = (idx4 & ((1u << 21) - 1)) * 4;
        src = (t == 0) ? q : (t == 1) ? k : v;
        dst = (t == 0) ? xq : (t == 1) ? xk : xv;
    } else {
        size_t w = idx4 - ((size_t)3 << 21);
        int t = (int)(w >> 18);
        off = (w & ((1u << 18) - 1)) * 4;
        src = (t == 0) ? wq : (t == 1) ? wk : (t == 2) ? wv : wo;
        dst = (t == 0) ? wqb : (t == 1) ? wkb : (t == 2) ? wvb : wob;
    }
    float4 val = *(const float4*)(src + off);
    ushort4 o;
    o.x = f2bf(val.x); o.y = f2bf(val.y); o.z = f2bf(val.z); o.w = f2bf(val.w);
    *(ushort4*)(dst + off) = o;
}

// ---------- GEMM: out[m,n] = sum_k A[m,k]*W[n,k] + bias[n] ----------
#define TM 128
#define TN 128

__device__ __forceinline__ void gemm_body(const u16* __restrict__ A,
                                          const u16* __restrict__ W,
                                          const float* __restrict__ bias,
                                          void* __restrict__ outp, int mode,
                                          int m0, int n0) {
    __shared__ __align__(16) u16 As[TM * 32];
    __shared__ __align__(16) u16 Bs[TN * 32];
    const int tid  = threadIdx.x;
    const int lane = tid & 63;
    const int wv   = tid >> 6;
    const int l16  = lane & 15;
    const int quad = lane >> 4;
    const int wm   = (wv >> 1) * 64;
    const int wn   = (wv & 1) * 64;

    f32x4 acc[4][4];
#pragma unroll
    for (int i = 0; i < 4; i++)
#pragma unroll
        for (int j = 0; j < 4; j++) acc[i][j] = {};

    const int arow = wv * 16 + (lane >> 2);
    const int acol = (lane & 3) * 8;
    const u16* gA = A + (size_t)(m0 + arow) * DMODEL + acol;
    const u16* gB = W + (size_t)(n0 + arow) * DMODEL + acol;
    u16* lA = As + wv * 16 * 32;   // wave-uniform
    u16* lB = Bs + wv * 16 * 32;

    for (int kb = 0; kb < DMODEL; kb += 32) {
        gld_lds16(gA + kb, lA);
        gld_lds16(gA + kb + (size_t)64 * DMODEL, lA + 64 * 32);
        gld_lds16(gB + kb, lB);
        gld_lds16(gB + kb + (size_t)64 * DMODEL, lB + 64 * 32);
        __builtin_amdgcn_s_waitcnt(0x0F70);   // vmcnt(0)
        __syncthreads();

        bf16x8 af[4], bfv[4];
#pragma unroll
        for (int i = 0; i < 4; i++)
            af[i] = *(const bf16x8*)(&As[(wm + i * 16 + l16) * 32 + quad * 8]);
#pragma unroll
        for (int j = 0; j < 4; j++)
            bfv[j] = *(const bf16x8*)(&Bs[(wn + j * 16 + l16) * 32 + quad * 8]);
#pragma unroll
        for (int i = 0; i < 4; i++)
#pragma unroll
            for (int j = 0; j < 4; j++)
                acc[i][j] = __builtin_amdgcn_mfma_f32_16x16x32_bf16(af[i], bfv[j], acc[i][j], 0, 0, 0);
        __syncthreads();
    }

#pragma unroll
    for (int j = 0; j < 4; j++) {
        int n = n0 + wn + j * 16 + l16;
        float bv = bias[n];
#pragma unroll
        for (int i = 0; i < 4; i++) {
            int mbase = m0 + wm + i * 16 + quad * 4;
#pragma unroll
            for (int r = 0; r < 4; r++) {
                int m = mbase + r;
                float v = acc[i][j][r] + bv;
                if (mode == 2) {
                    ((float*)outp)[(size_t)m * DMODEL + n] = v;
                } else {
                    int b = m >> 11, s = m & (S_LEN - 1);
                    int h = n >> 6, d = n & 63;
                    u16* o = (u16*)outp;
                    size_t idx = (mode == 0)
                        ? ((((size_t)(b * NHEAD + h)) * S_LEN + s) * HDIM + d)
                        : ((((size_t)(b * NHEAD + h)) * HDIM + d) * S_LEN + s);
                    o[idx] = f2bf(v);
                }
            }
        }
    }
}

// XCD-locality swizzle: hardware round-robins linear block id across 8 XCDs.
// XCD (lid&7) owns m-blocks [8*xcd, 8*xcd+8) for ALL n -> each A-tile is read
// by exactly one XCD; per-XCD working set = 2MB A + 2MB W ~= its 4MB L2.
__device__ __forceinline__ void gemm_coords(int& m0, int& n0) {
    const int lid = blockIdx.x + 8 * blockIdx.y;   // 0..511
    const int xcd = lid & 7;
    const int s   = lid >> 3;                      // 0..63
    n0 = (s & 7) * TN;
    m0 = ((s >> 3) + 8 * xcd) * TM;
}

__global__ __launch_bounds__(256) void gemm_qkv(
        const u16* __restrict__ xq, const u16* __restrict__ xk, const u16* __restrict__ xv,
        const u16* __restrict__ wq, const u16* __restrict__ wk, const u16* __restrict__ wv,
        const float* __restrict__ bq, const float* __restrict__ bk, const float* __restrict__ bv,
        u16* __restrict__ Qb, u16* __restrict__ Kb, u16* __restrict__ Vb) {
    int z = blockIdx.z;
    const u16* A   = (z == 0) ? xq : (z == 1) ? xk : xv;
    const u16* W   = (z == 0) ? wq : (z == 1) ? wk : wv;
    const float* b = (z == 0) ? bq : (z == 1) ? bk : bv;
    u16* out       = (z == 0) ? Qb : (z == 1) ? Kb : Vb;
    int m0, n0;
    gemm_coords(m0, n0);
    gemm_body(A, W, b, out, (z == 2) ? 1 : 0, m0, n0);
}

__global__ __launch_bounds__(256) void gemm_one(
        const u16* __restrict__ A, const u16* __restrict__ W,
        const float* __restrict__ bias, void* __restrict__ out, int mode) {
    int m0, n0;
    gemm_coords(m0, n0);
    gemm_body(A, W, bias, out, mode, m0, n0);
}

// ---------- flash attention v4 ----------
// v3 structure + raw v_exp_f32, incremental staging pointers, precomputed
// P-write offsets (kill the per-iter address VALU).
__global__ __launch_bounds__(256, 4) void flash_kernel(
        const u16* __restrict__ Q, const u16* __restrict__ K,
        const u16* __restrict__ Vt, u16* __restrict__ AO) {
    __shared__ __align__(16) u16 Ksm[2][64 * 64];
    __shared__ __align__(16) u16 Vsm[2][64 * 64];
    __shared__ __align__(16) u16 Psm[4][16 * 64];

    const int tid  = threadIdx.x;
    const int wv   = tid >> 6;
    const int lane = tid & 63;
    const int l16  = lane & 15;
    const int quad = lane >> 4;

    // XCD-pinning: all 16 blocks of a bh share (linear id % 8)
    const int lid   = blockIdx.x + 16 * blockIdx.y;   // 0..1023
    const int xcd   = lid & 7;
    const int slot  = lid >> 3;                        // 0..127
    const int bh    = xcd + 8 * (slot >> 4);           // 0..63
    const int g_idx = slot & 15;                       // 0..15

    const int h    = bh & (NHEAD - 1);
    const int b    = bh >> 4;
    const bool fwd = (h < 8);
    const int sgn  = fwd ? 1 : -1;
    const float slope2 = __builtin_amdgcn_exp2f(-(float)((h & 7) + 1) * 0.5731203125901445f)
                         * 1.4426950408889634f;
    const float cL = 0.18033688011112042f;   // log2(e)/8

    const u16* Kg = K + (size_t)bh * S_LEN * HDIM;
    const u16* Vg = Vt + (size_t)bh * HDIM * S_LEN;

    // staging lane constants: 8 lanes per row, col16 = (lane&7) ^ (lane>>3)
    const int sr = lane >> 3;
    const int sc = (lane & 7) ^ sr;
    const int r0 = 16 * wv;          // this wave stages rows r0..r0+15

    // fragment-read swizzled col16
    const int cA = quad ^ (l16 & 7);          // global col16 = quad
    const int cB = (quad + 4) ^ (l16 & 7);    // global col16 = quad+4

    // ALiBi per-(t,r) in-tile offset, fixed max 16 folded
    float brt[4][4];
#pragma unroll
    for (int t = 0; t < 4; t++)
#pragma unroll
        for (int r = 0; r < 4; r++)
            brt[t][r] = slope2 * (float)(sgn * (16 * t + l16 - (quad * 4 + r))) - 16.0f;

    // P scatter offsets (u16 units) — constant across all iterations
    int poff[4][4];
#pragma unroll
    for (int r = 0; r < 4; r++) {
        const int prow = quad * 4 + r;
        const int pr7  = prow & 7;
#pragma unroll
        for (int t = 0; t < 4; t++)
            poff[r][t] = prow * 64 + (((2 * t + (l16 >> 3)) ^ pr7) * 8) + (l16 & 7);
    }

    bf16x8 ones;
#pragma unroll
    for (int j = 0; j < 8; j++) ones[j] = (__bf16)1.0f;

    const float dkq = slope2 * (float)(sgn * 64);

#pragma unroll 1
    for (int half = 0; half < 2; half++) {
        const int g  = half ? (31 - g_idx) : g_idx;    // 64-query group 0..31
        const int q0 = g * 64 + wv * 16;
        const u16* Qp = Q + ((size_t)bh * S_LEN + q0) * HDIM;
        const bf16x8 aq0 = *(const bf16x8*)(Qp + l16 * HDIM + quad * 8);
        const bf16x8 aq1 = *(const bf16x8*)(Qp + l16 * HDIM + 32 + quad * 8);

        f32x4 o[4], osum = {};
#pragma unroll
        for (int dt = 0; dt < 4; dt++) o[dt] = {};

        const int kt0 = fwd ? 0 : g;
        const int kt1 = fwd ? g : (S_LEN / 64 - 1);

        __syncthreads();   // previous half's readers done before overwrite
        // incremental staging pointers
        const u16* kg = Kg + ((size_t)(kt0 * 64) + r0 + sr) * 64 + sc * 8;
        const u16* vg = Vg + (size_t)(r0 + sr) * S_LEN + kt0 * 64 + sc * 8;
        gld_lds16(kg,              &Ksm[0][r0 * 64]);
        gld_lds16(kg + 8 * 64,     &Ksm[0][(r0 + 8) * 64]);
        gld_lds16(vg,              &Vsm[0][r0 * 64]);
        gld_lds16(vg + 8 * S_LEN,  &Vsm[0][(r0 + 8) * 64]);
        kg += 64 * 64;
        vg += 64;

        float kq = slope2 * (float)(sgn * (kt0 * 64 - q0));

        int buf = 0;
        for (int kt = kt0; kt <= kt1; ++kt) {
            __builtin_amdgcn_s_waitcnt(0x0F70);   // vmcnt(0): buf staged
            __syncthreads();
            if (kt < kt1) {   // stage next tile into the other buffer
                gld_lds16(kg,             &Ksm[buf ^ 1][r0 * 64]);
                gld_lds16(kg + 8 * 64,    &Ksm[buf ^ 1][(r0 + 8) * 64]);
                gld_lds16(vg,             &Vsm[buf ^ 1][r0 * 64]);
                gld_lds16(vg + 8 * S_LEN, &Vsm[buf ^ 1][(r0 + 8) * 64]);
                kg += 64 * 64;
                vg += 64;
            }
            const u16* Ks = &Ksm[buf][0];
            const u16* Vs = &Vsm[buf][0];

            // QK^T from LDS
            f32x4 st[4];
#pragma unroll
            for (int t = 0; t < 4; t++) {
                const u16* kp = Ks + (16 * t + l16) * 64;
                bf16x8 k0 = *(const bf16x8*)(kp + cA * 8);
                bf16x8 k1 = *(const bf16x8*)(kp + cB * 8);
                f32x4 c = {};
                c = __builtin_amdgcn_mfma_f32_16x16x32_bf16(aq0, k0, c, 0, 0, 0);
                c = __builtin_amdgcn_mfma_f32_16x16x32_bf16(aq1, k1, c, 0, 0, 0);
                st[t] = c;
            }

            float p[4][4];
            if (kt == g) {   // diagonal tile: explicit mask
#pragma unroll
                for (int r = 0; r < 4; r++) {
                    const int qg = q0 + quad * 4 + r;
#pragma unroll
                    for (int t = 0; t < 4; t++) {
                        const int kg2 = kt * 64 + 16 * t + l16;
                        const bool ok = fwd ? (kg2 <= qg) : (kg2 >= qg);
                        float s2 = fmaf(st[t][r], cL, brt[t][r] + kq);
                        p[t][r] = ok ? __builtin_amdgcn_exp2f(s2) : 0.0f;
                    }
                }
            } else {
#pragma unroll
                for (int r = 0; r < 4; r++)
#pragma unroll
                    for (int t = 0; t < 4; t++)
                        p[t][r] = __builtin_amdgcn_exp2f(fmaf(st[t][r], cL, brt[t][r] + kq));
            }
            kq += dkq;

            // P (C-layout) -> swizzled LDS -> A-operand layout (wave-private)
            u16* Pw = &Psm[wv][0];
#pragma unroll
            for (int r = 0; r < 4; r++)
#pragma unroll
                for (int t = 0; t < 4; t++)
                    Pw[poff[r][t]] = f2bf(p[t][r]);
            __builtin_amdgcn_s_waitcnt(0xC07F);   // lgkmcnt(0); wave-private
            bf16x8 pf0 = *(const bf16x8*)(&Pw[l16 * 64 + cA * 8]);
            bf16x8 pf1 = *(const bf16x8*)(&Pw[l16 * 64 + cB * 8]);

            // PV from LDS V
#pragma unroll
            for (int dt = 0; dt < 4; dt++) {
                const u16* vp = Vs + (dt * 16 + l16) * 64;
                bf16x8 v0 = *(const bf16x8*)(vp + cA * 8);
                bf16x8 v1 = *(const bf16x8*)(vp + cB * 8);
                o[dt] = __builtin_amdgcn_mfma_f32_16x16x32_bf16(pf0, v0, o[dt], 0, 0, 0);
                o[dt] = __builtin_amdgcn_mfma_f32_16x16x32_bf16(pf1, v1, o[dt], 0, 0, 0);
            }
            osum = __builtin_amdgcn_mfma_f32_16x16x32_bf16(pf0, ones, osum, 0, 0, 0);
            osum = __builtin_amdgcn_mfma_f32_16x16x32_bf16(pf1, ones, osum, 0, 0, 0);
            buf ^= 1;
        }

        // epilogue: AO[b, s, h*64+d] bf16
#pragma unroll
        for (int r = 0; r < 4; r++) {
            float inv = 1.0f / osum[r];
            int qg = q0 + quad * 4 + r;
            u16* op = AO + ((size_t)b * S_LEN + qg) * DMODEL + h * HDIM;
#pragma unroll
            for (int dt = 0; dt < 4; dt++)
                op[dt * 16 + l16] = f2bf(o[dt][r] * inv);
        }
    }
}

extern "C" void kernel_launch(void* const* d_in, const int* in_sizes, int n_in,
                              void* d_out, int out_size, void* d_ws, size_t ws_size,
                              hipStream_t stream) {
    const float* query = (const float*)d_in[0];
    const float* key   = (const float*)d_in[1];
    const float* value = (const float*)d_in[2];
    const float* Wq    = (const float*)d_in[3];
    const float* bq    = (const float*)d_in[4];
    const float* Wk    = (const float*)d_in[5];
    const float* bk    = (const float*)d_in[6];
    const float* Wv    = (const float*)d_in[7];
    const float* bv    = (const float*)d_in[8];
    const float* Wo    = (const float*)d_in[9];
    const float* bo    = (const float*)d_in[10];

    const size_t Xe = (size_t)MTOK * DMODEL;    // 2^23 elems
    const size_t We = (size_t)DMODEL * DMODEL;  // 2^20 elems
    u16* xq  = (u16*)d_ws;
    u16* xk  = xq + Xe;
    u16* xv  = xk + Xe;
    u16* wqb = xv + Xe;
    u16* wkb = wqb + We;
    u16* wvb = wkb + We;
    u16* wob = wvb + We;
    u16* Qb  = wob + We;
    u16* Kb  = Qb + Xe;
    u16* Vb  = Kb + Xe;   // transposed [B,H,D,S]
    u16* AO  = Vb + Xe;

    // fused cast: (3*2^21 + 4*2^18) float4 groups / 256 = 28672 blocks
    cast_all<<<dim3(28672), dim3(256), 0, stream>>>(
        query, key, value, Wq, Wk, Wv, Wo,
        xq, xk, xv, wqb, wkb, wvb, wob);

    gemm_qkv<<<dim3(DMODEL / TN, MTOK / TM, 3), dim3(256), 0, stream>>>(
        xq, xk, xv, wqb, wkb, wvb, bq, bk, bv, Qb, Kb, Vb);

    flash_kernel<<<dim3(16, NBATCH * NHEAD), dim3(256), 0, stream>>>(Qb, Kb, Vb, AO);

    gemm_one<<<dim3(DMODEL / TN, MTOK / TM, 1), dim3(256), 0, stream>>>(AO, wob, bo, d_out, 2);
}